// Round 8
// baseline (577.749 us; speedup 1.0000x reference)
//
#include <hip/hip_runtime.h>
#include <hip/hip_bf16.h>

typedef unsigned short ushort_t;
using bf16x8 = __attribute__((ext_vector_type(8))) short;
using f32x4  = __attribute__((ext_vector_type(4))) float;

#define DEV __device__ __forceinline__

DEV unsigned short f2bf(float f) {
    unsigned int u = __builtin_bit_cast(unsigned int, f);
    u = (u + 0x7fffu + ((u >> 16) & 1u)) >> 16;
    return (unsigned short)u;
}

DEV int cvtpk_bf16(float lo, float hi) {
    int r;
    asm("v_cvt_pk_bf16_f32 %0, %1, %2" : "=v"(r) : "v"(lo), "v"(hi));
    return r;
}

DEV void gload16(const unsigned short* g, unsigned short* l) {
    __builtin_amdgcn_global_load_lds(
        (const __attribute__((address_space(1))) void*)g,
        (__attribute__((address_space(3))) void*)l, 16, 0, 0);
}

// tanh-form GELU
DEV float gelu_f(float v) {
    float u = v * (0.79788456f + 0.03567741f * v * v);
    float t = __builtin_amdgcn_exp2f(u * 2.88539008f);
    return v * t * __builtin_amdgcn_rcpf(t + 1.0f);
}

// ---------------- f32 -> bf16 convert ----------------
__global__ __launch_bounds__(256) void cvtbf_kernel(const float* __restrict__ in,
                                                    unsigned short* __restrict__ out) {
    int i = (blockIdx.x * 256 + threadIdx.x) * 4;
    float4 v = *(const float4*)&in[i];
    out[i + 0] = f2bf(v.x);
    out[i + 1] = f2bf(v.y);
    out[i + 2] = f2bf(v.z);
    out[i + 3] = f2bf(v.w);
}

// ---------------- transpose + convert: in[R,C] f32 -> out[C,R] bf16 ----------------
__global__ __launch_bounds__(256) void transpose_cvt_kernel(const float* __restrict__ in,
                                                            unsigned short* __restrict__ out,
                                                            int R, int C) {
    __shared__ float t[32][33];
    int tx = threadIdx.x, ty = threadIdx.y;
    int c0 = blockIdx.x * 32, r0 = blockIdx.y * 32;
#pragma unroll
    for (int i = 0; i < 4; ++i)
        t[ty + i * 8][tx] = in[(size_t)(r0 + ty + i * 8) * C + c0 + tx];
    __syncthreads();
#pragma unroll
    for (int i = 0; i < 4; ++i)
        out[(size_t)(c0 + ty + i * 8) * R + r0 + tx] = f2bf(t[tx][ty + i * 8]);
}

// ---------------- V transpose: qkvb V-part -> vtg[bh][64][2048] bf16 ----------------
__global__ __launch_bounds__(256) void vtrans_kernel(const unsigned short* __restrict__ qkvb,
                                                     unsigned short* __restrict__ vtg) {
    __shared__ unsigned short t[64 * 66];
    const int tid = threadIdx.x;
    const int t0 = blockIdx.x * 64;
    const int bh = blockIdx.y;
    const int b = bh >> 4, h = bh & 15;
    const unsigned short* src = qkvb + (size_t)(b * 2048 + t0) * 3072 + 2048 + h * 64;
#pragma unroll
    for (int c = 0; c < 2; ++c) {
        int cid = c * 256 + tid;
        int row = cid >> 3, cc = cid & 7;
        *(int4*)&t[row * 66 + cc * 8] = *(const int4*)&src[(size_t)row * 3072 + cc * 8];
    }
    __syncthreads();
    unsigned short* dst = vtg + (size_t)bh * 64 * 2048 + t0;
#pragma unroll
    for (int c = 0; c < 2; ++c) {
        int cid = c * 256 + tid;
        int d = cid >> 3, cc2 = cid & 7;
        bf16x8 v;
#pragma unroll
        for (int j = 0; j < 8; ++j) v[j] = (short)t[(cc2 * 8 + j) * 66 + d];
        *(bf16x8*)&dst[(size_t)d * 2048 + cc2 * 8] = v;
    }
}

// ---------------- GEMM 128x128, BK=64, 4 waves (2x2), 2 blocks/CU (TLP) -------------
// LDS 64KB dbuf. Phase ks: {vmcnt(4); barrier; ds_read 8 b128; stage 4-load K-half
// group of tile t+1; setprio; 16 MFMA}. Ledger: entry ks0: out=[G0(t),G1(t)]=8 ->
// vmcnt(4) drains G0. entry ks1: out=[G1(t),G0(t+1)]=8 -> vmcnt(4) drains G1.
// 4 loads always in flight; vmcnt(0) only at last tile. TLP: co-resident block's
// MFMA covers this block's drains (m114).
template <int ACT, int OBF>
__global__ __launch_bounds__(256, 2) void gemm_kernel(
    const unsigned short* __restrict__ A, const unsigned short* __restrict__ Bt,
    const float* __restrict__ bias, void* __restrict__ out,
    int N, int K, int gridNt) {
    __shared__ __align__(16) unsigned short lA[2][128 * 64];
    __shared__ __align__(16) unsigned short lB[2][128 * 64];
    const int tid = threadIdx.x;
    const int lane = tid & 63, wid = tid >> 6;
    const int g = lane >> 4, lr = lane & 15;
    const int wm = wid >> 1, wn = wid & 1;

    // XCD-aware bijective swizzle; mt-outer (consecutive wkid share the A-panel)
    const int nwg = gridDim.x, cpx = nwg >> 3, bid = blockIdx.x;
    const int wkid = (bid & 7) * cpx + (bid >> 3);
    const int mt = wkid / gridNt, nt = wkid % gridNt;
    const int m0 = mt * 128, n0 = nt * 128;

    auto stageA = [&](int s, int kt, int bb) {  // s in [0,4): covers kb 2s,2s+1
        int c = s * 256 + tid;
        int row = c & 127, kb = c >> 7;
        gload16(&A[(size_t)(m0 + row) * K + kt * 64 + kb * 8],
                &lA[bb][(size_t)(s * 256 + (tid & ~63)) * 8]);
    };
    auto stageB = [&](int s, int kt, int bb) {
        int c = s * 256 + tid;
        int row = c & 127, kb = c >> 7;
        gload16(&Bt[(size_t)(n0 + row) * K + kt * 64 + kb * 8],
                &lB[bb][(size_t)(s * 256 + (tid & ~63)) * 8]);
    };

    f32x4 acc[4][4] = {};
    const int nkt = K >> 6;

    // prologue: tile 0, group order G0={A0,A1,B0,B1} (kb0-3), G1={A2,A3,B2,B3}
    stageA(0, 0, 0); stageA(1, 0, 0); stageB(0, 0, 0); stageB(1, 0, 0);
    stageA(2, 0, 0); stageA(3, 0, 0); stageB(2, 0, 0); stageB(3, 0, 0);

    for (int kt = 0; kt < nkt; ++kt) {
        const int buf = kt & 1;
        const bool more = (kt + 1 < nkt);
#pragma unroll
        for (int ks = 0; ks < 2; ++ks) {
            if (ks == 1 && !more)
                asm volatile("s_waitcnt vmcnt(0)" ::: "memory");
            else
                asm volatile("s_waitcnt vmcnt(4)" ::: "memory");
            __builtin_amdgcn_s_barrier();
            asm volatile("" ::: "memory");  // keep LDS reads below the barrier
            bf16x8 af[4], bfr[4];
#pragma unroll
            for (int mf = 0; mf < 4; ++mf) {
                int c = (ks * 4 + g) * 128 + wm * 64 + mf * 16 + lr;
                af[mf] = *(const bf16x8*)&lA[buf][(size_t)c * 8];
            }
#pragma unroll
            for (int nf = 0; nf < 4; ++nf) {
                int c = (ks * 4 + g) * 128 + wn * 64 + nf * 16 + lr;
                bfr[nf] = *(const bf16x8*)&lB[buf][(size_t)c * 8];
            }
            if (more) {
                if (ks == 0) { stageA(0, kt + 1, buf ^ 1); stageA(1, kt + 1, buf ^ 1);
                               stageB(0, kt + 1, buf ^ 1); stageB(1, kt + 1, buf ^ 1); }
                else         { stageA(2, kt + 1, buf ^ 1); stageA(3, kt + 1, buf ^ 1);
                               stageB(2, kt + 1, buf ^ 1); stageB(3, kt + 1, buf ^ 1); }
            }
            __builtin_amdgcn_s_setprio(1);
#pragma unroll
            for (int mf = 0; mf < 4; ++mf)
#pragma unroll
                for (int nf = 0; nf < 4; ++nf)
                    acc[mf][nf] = __builtin_amdgcn_mfma_f32_16x16x32_bf16(
                        af[mf], bfr[nf], acc[mf][nf], 0, 0, 0);
            __builtin_amdgcn_s_setprio(0);
        }
    }

    // epilogue: bias (+GELU) and store
#pragma unroll
    for (int mf = 0; mf < 4; ++mf) {
#pragma unroll
        for (int nf = 0; nf < 4; ++nf) {
            int col = n0 + wn * 64 + nf * 16 + lr;
            float bv = bias[col];
#pragma unroll
            for (int r = 0; r < 4; ++r) {
                int row = m0 + wm * 64 + mf * 16 + g * 4 + r;
                float v = acc[mf][nf][r] + bv;
                if (ACT == 1) v = gelu_f(v);
                if (OBF)
                    ((unsigned short*)out)[(size_t)row * N + col] = f2bf(v);
                else
                    ((float*)out)[(size_t)row * N + col] = v;
            }
        }
    }
}

// ---------------- flash attention v4: KVBLK=128, defer-max, bh->XCD affinity --------
__global__ __launch_bounds__(256, 2) void attn_kernel(const unsigned short* __restrict__ qkv,
                                                      const unsigned short* __restrict__ vtg,
                                                      unsigned short* __restrict__ y) {
    __shared__ unsigned short Kl[2][128 * 64];
    __shared__ unsigned short Vl[2][64 * 128];
    const int tid = threadIdx.x, lane = tid & 63, w = tid >> 6;
    const int g = lane >> 4, lr = lane & 15;
    // bh->XCD affinity: all 8 p-blocks of one (b,h) share id%8 -> same XCD L2
    const int id = blockIdx.x + 8 * (blockIdx.y + 16 * blockIdx.z);
    const int xcd = id & 7, wrk = id >> 3;
    const int bh = xcd * 8 + (wrk & 7);
    const int p = wrk >> 3;
    const int b = bh >> 4, h = bh & 15;
    const size_t rs3 = 3072;
    const unsigned short* qbase = qkv + (size_t)b * 2048 * rs3 + h * 64;
    const unsigned short* kbase = qbase + 1024;
    const unsigned short* vbase = vtg + (size_t)bh * 64 * 2048;

    // staging offsets (source-swizzled, linear LDS dest)
    int ksoff[4], vsoff[4], ldoff[4];
#pragma unroll
    for (int c = 0; c < 4; ++c) {
        int cid = c * 256 + tid;
        int krow = cid >> 3, kcc = cid & 7;
        ksoff[c] = krow * 3072 + (kcc ^ (krow & 7) ^ ((krow >> 3) & 7)) * 8;
        int d = cid >> 4, tcs = cid & 15;
        vsoff[c] = d * 2048 + (tcs ^ ((d & 7) ^ ((d >> 3) & 7))) * 8;
        ldoff[c] = (c * 256 + (tid & ~63)) * 8;
    }

    const int idxP0 = 4 * (32 * (g & 1) + lr);
    const int idxP1 = idxP0 + 64;
    int idxA[4];
#pragma unroll
    for (int r = 0; r < 4; ++r) idxA[r] = 4 * (g * 20 + r);
    const bool ghigh = (g >> 1) != 0;
    const float qscale = 0.125f * 1.44269504089f;

    auto process = [&](int J) {
        const int q0w = J * 128 + w * 32;
        const int ktend = J + 1;
        // prologue: stage super-tile 0
#pragma unroll
        for (int c = 0; c < 4; ++c) {
            gload16(&kbase[ksoff[c]], &Kl[0][ldoff[c]]);
            gload16(&vbase[vsoff[c]], &Vl[0][ldoff[c]]);
        }
        int qf[2][2][4];
#pragma unroll
        for (int sub = 0; sub < 2; ++sub)
#pragma unroll
            for (int f = 0; f < 2; ++f) {
                int4 v = *(const int4*)&qbase[(size_t)(q0w + sub * 16 + lr) * rs3 + f * 32 + g * 8];
                int vv[4] = {v.x, v.y, v.z, v.w};
#pragma unroll
                for (int i = 0; i < 4; ++i) {
                    unsigned int u = (unsigned int)vv[i];
                    float lo = __builtin_bit_cast(float, u << 16) * qscale;
                    float hi = __builtin_bit_cast(float, u & 0xffff0000u) * qscale;
                    qf[sub][f][i] = cvtpk_bf16(lo, hi);
                }
            }

        f32x4 O[2][4] = {};
        float m_[2] = {-3.0e38f, -3.0e38f}, l_[2] = {0.f, 0.f};

        int buf = 0;
        for (int kt = 0; kt < ktend; ++kt) {
            asm volatile("s_waitcnt vmcnt(0)" ::: "memory");
            __builtin_amdgcn_s_barrier();
            asm volatile("" ::: "memory");
            if (kt + 1 < ktend) {
#pragma unroll
                for (int c = 0; c < 4; ++c) {
                    gload16(&kbase[(size_t)(kt + 1) * 128 * 3072 + ksoff[c]], &Kl[buf ^ 1][ldoff[c]]);
                    gload16(&vbase[vsoff[c] + (kt + 1) * 128], &Vl[buf ^ 1][ldoff[c]]);
                }
            }
            const unsigned short* Kc = Kl[buf];
            const unsigned short* Vc = Vl[buf];

            // QK^T swapped: S^T, 8 key-subtiles of 16
            f32x4 s0[8], s1[8];
#pragma unroll
            for (int st = 0; st < 8; ++st) {
                int rbase = (st * 16 + lr) * 64;
                int sw = (lr & 7) ^ ((st * 2 + (lr >> 3)) & 7);
                bf16x8 kf0 = *(const bf16x8*)&Kc[rbase + ((g ^ sw) * 8)];
                bf16x8 kf1 = *(const bf16x8*)&Kc[rbase + (((4 + g) ^ sw) * 8)];
                f32x4 a = {};
                a = __builtin_amdgcn_mfma_f32_16x16x32_bf16(kf0, *(const bf16x8*)&qf[0][0], a, 0, 0, 0);
                a = __builtin_amdgcn_mfma_f32_16x16x32_bf16(kf1, *(const bf16x8*)&qf[0][1], a, 0, 0, 0);
                s0[st] = a;
                f32x4 c = {};
                c = __builtin_amdgcn_mfma_f32_16x16x32_bf16(kf0, *(const bf16x8*)&qf[1][0], c, 0, 0, 0);
                c = __builtin_amdgcn_mfma_f32_16x16x32_bf16(kf1, *(const bf16x8*)&qf[1][1], c, 0, 0, 0);
                s1[st] = c;
            }

            int wt0[4][4], wt1[4][4];
#pragma unroll
            for (int sub = 0; sub < 2; ++sub) {
                f32x4* s = (sub == 0) ? s0 : s1;
                const int qmin = q0w + sub * 16;
                if (kt == J) {  // diagonal super-tile: causal mask
                    int qv = qmin + lr;
#pragma unroll
                    for (int st = 0; st < 8; ++st) {
                        int keyb = kt * 128 + st * 16 + g * 4;
#pragma unroll
                        for (int r = 0; r < 4; ++r)
                            if (keyb + r > qv) s[st][r] = -3.0e38f;
                    }
                }
                float mx = fmaxf(fmaxf(s[0][0], s[0][1]), fmaxf(s[0][2], s[0][3]));
#pragma unroll
                for (int st = 1; st < 8; ++st)
                    mx = fmaxf(mx, fmaxf(fmaxf(s[st][0], s[st][1]), fmaxf(s[st][2], s[st][3])));
                mx = fmaxf(mx, __shfl_xor(mx, 16));
                mx = fmaxf(mx, __shfl_xor(mx, 32));
                // defer-max (T13): rescale only when max grows by > ~8 nats (11.5 log2)
                if (__any(mx - m_[sub] > 11.5f)) {
                    float mnew = fmaxf(m_[sub], mx);
                    float alpha = __builtin_amdgcn_exp2f(m_[sub] - mnew);
                    m_[sub] = mnew;
                    l_[sub] *= alpha;
                    int av = __builtin_bit_cast(int, alpha);
                    f32x4* Os = O[sub];
#pragma unroll
                    for (int r = 0; r < 4; ++r) {
                        float ar = __builtin_bit_cast(float, __builtin_amdgcn_ds_bpermute(idxA[r], av));
#pragma unroll
                        for (int dt = 0; dt < 4; ++dt) Os[dt][r] *= ar;
                    }
                }
                float rs = 0.f;
#pragma unroll
                for (int st = 0; st < 8; ++st)
#pragma unroll
                    for (int r = 0; r < 4; ++r) {
                        float pp = __builtin_amdgcn_exp2f(s[st][r] - m_[sub]);
                        s[st][r] = pp;
                        rs += pp;
                    }
                rs += __shfl_xor(rs, 16);
                rs += __shfl_xor(rs, 32);
                l_[sub] += rs;
                int ws_[8][2];
#pragma unroll
                for (int st = 0; st < 8; ++st) {
                    ws_[st][0] = cvtpk_bf16(s[st][0], s[st][1]);
                    ws_[st][1] = cvtpk_bf16(s[st][2], s[st][3]);
                }
                int(*wt)[4] = (sub == 0) ? wt0 : wt1;
#pragma unroll
                for (int ks = 0; ks < 4; ++ks)
#pragma unroll
                    for (int hp = 0; hp < 4; ++hp) {
                        int idx = (hp < 2) ? idxP0 : idxP1;
                        int v0 = __builtin_amdgcn_ds_bpermute(idx, ws_[2 * ks][hp & 1]);
                        int v1 = __builtin_amdgcn_ds_bpermute(idx, ws_[2 * ks + 1][hp & 1]);
                        wt[ks][hp] = ghigh ? v1 : v0;
                    }
            }

            // PV: 4 k-slots of 32
#pragma unroll
            for (int ks = 0; ks < 4; ++ks) {
                bf16x8 pa0 = *(const bf16x8*)&wt0[ks][0];
                bf16x8 pa1 = *(const bf16x8*)&wt1[ks][0];
#pragma unroll
                for (int dt = 0; dt < 4; ++dt) {
                    int d = dt * 16 + lr;
                    int tc = (ks * 4 + g) ^ ((lr & 7) ^ ((dt * 2 + (lr >> 3)) & 7));
                    bf16x8 vf = *(const bf16x8*)&Vc[d * 128 + tc * 8];
                    O[0][dt] = __builtin_amdgcn_mfma_f32_16x16x32_bf16(pa0, vf, O[0][dt], 0, 0, 0);
                    O[1][dt] = __builtin_amdgcn_mfma_f32_16x16x32_bf16(pa1, vf, O[1][dt], 0, 0, 0);
                }
            }
            buf ^= 1;
        }

        // epilogue
#pragma unroll
        for (int sub = 0; sub < 2; ++sub) {
            int lv = __builtin_bit_cast(int, l_[sub]);
#pragma unroll
            for (int r = 0; r < 4; ++r) {
                float lval = __builtin_bit_cast(float, __builtin_amdgcn_ds_bpermute(idxA[r], lv));
                float inv = __builtin_amdgcn_rcpf(lval);
                int q = q0w + sub * 16 + g * 4 + r;
#pragma unroll
                for (int dt = 0; dt < 4; ++dt)
                    y[(size_t)(b * 2048 + q) * 1024 + h * 64 + dt * 16 + lr] =
                        f2bf(O[sub][dt][r] * inv);
            }
        }
    };

    process(15 - p);
    __syncthreads();
    process(p);
}

// ---------------- residual + layernorm: out = base + LN(delta)*g+b ----------------
template <int WRITE_BF>
__global__ __launch_bounds__(256) void ln_kernel(const float* __restrict__ base,
                                                 const float* __restrict__ delta,
                                                 const float* __restrict__ gw,
                                                 const float* __restrict__ bw,
                                                 float* __restrict__ outf,
                                                 unsigned short* __restrict__ outb) {
    const int row = blockIdx.x;
    const int tid = threadIdx.x;
    const float* d = delta + (size_t)row * 1024;
    const float* bs = base + (size_t)row * 1024;
    float4 x = *(const float4*)&d[tid * 4];
    float s = x.x + x.y + x.z + x.w;
    float s2 = x.x * x.x + x.y * x.y + x.z * x.z + x.w * x.w;
#pragma unroll
    for (int off = 1; off < 64; off <<= 1) {
        s += __shfl_xor(s, off);
        s2 += __shfl_xor(s2, off);
    }
    __shared__ float red[8];
    if ((tid & 63) == 0) {
        red[tid >> 6] = s;
        red[4 + (tid >> 6)] = s2;
    }
    __syncthreads();
    s = red[0] + red[1] + red[2] + red[3];
    s2 = red[4] + red[5] + red[6] + red[7];
    float mu = s * (1.f / 1024.f);
    float var = s2 * (1.f / 1024.f) - mu * mu;
    float rsig = rsqrtf(var + 1e-5f);
    float4 bb = *(const float4*)&bs[tid * 4];
    float4 gv = *(const float4*)&gw[tid * 4];
    float4 bv = *(const float4*)&bw[tid * 4];
    float4 o;
    o.x = bb.x + (x.x - mu) * rsig * gv.x + bv.x;
    o.y = bb.y + (x.y - mu) * rsig * gv.y + bv.y;
    o.z = bb.z + (x.z - mu) * rsig * gv.z + bv.z;
    o.w = bb.w + (x.w - mu) * rsig * gv.w + bv.w;
    *(float4*)&outf[(size_t)row * 1024 + tid * 4] = o;
    if (WRITE_BF) {
        unsigned short* ob = outb + (size_t)row * 1024 + tid * 4;
        ob[0] = f2bf(o.x);
        ob[1] = f2bf(o.y);
        ob[2] = f2bf(o.z);
        ob[3] = f2bf(o.w);
    }
}

extern "C" void kernel_launch(void* const* d_in, const int* in_sizes, int n_in,
                              void* d_out, int out_size, void* d_ws, size_t ws_size,
                              hipStream_t stream) {
    const float* x = (const float*)d_in[0];
    const float* w_qkv = (const float*)d_in[1];
    const float* b_qkv = (const float*)d_in[2];
    const float* w_out = (const float*)d_in[3];
    const float* b_out = (const float*)d_in[4];
    const float* w1 = (const float*)d_in[5];
    const float* b1 = (const float*)d_in[6];
    const float* w2 = (const float*)d_in[7];
    const float* b2 = (const float*)d_in[8];
    const float* g1 = (const float*)d_in[9];
    const float* be1 = (const float*)d_in[10];
    const float* g2 = (const float*)d_in[11];
    const float* be2 = (const float*)d_in[12];

    const size_t MB = 1ull << 20;
    if (ws_size < 184 * MB) return;
    char* ws = (char*)d_ws;
    unsigned short* xb    = (unsigned short*)(ws + 0);         // 16MB (dead after qkv gemm)
    unsigned short* vtg   = (unsigned short*)(ws + 0);         // 16MB (V^T, lives during attn)
    unsigned short* wqkvt = (unsigned short*)(ws + 16 * MB);   // 6MB
    unsigned short* qkvb  = (unsigned short*)(ws + 22 * MB);   // 48MB
    unsigned short* hb    = (unsigned short*)(ws + 0);         // 64MB (reuse, MLP phase)
    unsigned short* woutt = (unsigned short*)(ws + 70 * MB);   // 2MB
    unsigned short* yb    = (unsigned short*)(ws + 72 * MB);   // 16MB
    float*          attnp = (float*)(ws + 88 * MB);            // 32MB
    float*          ff    = (float*)(ws + 88 * MB);            // 32MB (reuse)
    float*          x2f   = (float*)(ws + 120 * MB);           // 32MB
    unsigned short* x2b   = (unsigned short*)(ws + 152 * MB);  // 16MB
    unsigned short* w1t   = (unsigned short*)(ws + 168 * MB);  // 8MB
    unsigned short* w2t   = (unsigned short*)(ws + 176 * MB);  // 8MB

    // prep
    cvtbf_kernel<<<8192, 256, 0, stream>>>(x, xb);
    transpose_cvt_kernel<<<dim3(96, 32), dim3(32, 8), 0, stream>>>(w_qkv, wqkvt, 1024, 3072);
    transpose_cvt_kernel<<<dim3(32, 32), dim3(32, 8), 0, stream>>>(w_out, woutt, 1024, 1024);
    transpose_cvt_kernel<<<dim3(128, 32), dim3(32, 8), 0, stream>>>(w1, w1t, 1024, 4096);
    transpose_cvt_kernel<<<dim3(32, 128), dim3(32, 8), 0, stream>>>(w2, w2t, 4096, 1024);
    // qkv = x @ w_qkv + b_qkv (bf16 out) [M=8192 N=3072 K=1024]: 64mt x 24nt
    gemm_kernel<0, 1><<<1536, 256, 0, stream>>>(xb, wqkvt, b_qkv, qkvb, 3072, 1024, 24);
    // V^T pre-transpose
    vtrans_kernel<<<dim3(32, 64), 256, 0, stream>>>(qkvb, vtg);
    // attention
    attn_kernel<<<dim3(8, 16, 4), 256, 0, stream>>>(qkvb, vtg, yb);
    // out proj (f32 out) [N=1024 K=1024]: 64mt x 8nt
    gemm_kernel<0, 0><<<512, 256, 0, stream>>>(yb, woutt, b_out, attnp, 1024, 1024, 8);
    // x2 = x + LN(attnp)
    ln_kernel<1><<<8192, 256, 0, stream>>>(x, attnp, g1, be1, x2f, x2b);
    // h = gelu(x2 @ w1 + b1) (bf16 out) [N=4096 K=1024]: 64mt x 32nt
    gemm_kernel<1, 1><<<2048, 256, 0, stream>>>(x2b, w1t, b1, hb, 4096, 1024, 32);
    // f = h @ w2 + b2 (f32 out) [N=1024 K=4096]: 64mt x 8nt
    gemm_kernel<0, 0><<<512, 256, 0, stream>>>(hb, w2t, b2, ff, 1024, 4096, 8);
    // out = x2 + LN(f)
    ln_kernel<0><<<8192, 256, 0, stream>>>(x2f, ff, g2, be2, (float*)d_out, nullptr);
}

// Round 9
// 470.959 us; speedup vs baseline: 1.2268x; 1.2268x over previous
//
#include <hip/hip_runtime.h>
#include <hip/hip_bf16.h>

typedef unsigned short ushort_t;
using bf16x8 = __attribute__((ext_vector_type(8))) short;
using f32x4  = __attribute__((ext_vector_type(4))) float;

#define DEV __device__ __forceinline__

DEV unsigned short f2bf(float f) {
    unsigned int u = __builtin_bit_cast(unsigned int, f);
    u = (u + 0x7fffu + ((u >> 16) & 1u)) >> 16;
    return (unsigned short)u;
}

DEV int cvtpk_bf16(float lo, float hi) {
    int r;
    asm("v_cvt_pk_bf16_f32 %0, %1, %2" : "=v"(r) : "v"(lo), "v"(hi));
    return r;
}

DEV void gload16(const unsigned short* g, unsigned short* l) {
    __builtin_amdgcn_global_load_lds(
        (const __attribute__((address_space(1))) void*)g,
        (__attribute__((address_space(3))) void*)l, 16, 0, 0);
}

// tanh-form GELU
DEV float gelu_f(float v) {
    float u = v * (0.79788456f + 0.03567741f * v * v);
    float t = __builtin_amdgcn_exp2f(u * 2.88539008f);
    return v * t * __builtin_amdgcn_rcpf(t + 1.0f);
}

// ---------------- f32 -> bf16 convert ----------------
__global__ __launch_bounds__(256) void cvtbf_kernel(const float* __restrict__ in,
                                                    unsigned short* __restrict__ out) {
    int i = (blockIdx.x * 256 + threadIdx.x) * 4;
    float4 v = *(const float4*)&in[i];
    out[i + 0] = f2bf(v.x);
    out[i + 1] = f2bf(v.y);
    out[i + 2] = f2bf(v.z);
    out[i + 3] = f2bf(v.w);
}

// ---------------- transpose + convert: in[R,C] f32 -> out[C,R] bf16 ----------------
__global__ __launch_bounds__(256) void transpose_cvt_kernel(const float* __restrict__ in,
                                                            unsigned short* __restrict__ out,
                                                            int R, int C) {
    __shared__ float t[32][33];
    int tx = threadIdx.x, ty = threadIdx.y;
    int c0 = blockIdx.x * 32, r0 = blockIdx.y * 32;
#pragma unroll
    for (int i = 0; i < 4; ++i)
        t[ty + i * 8][tx] = in[(size_t)(r0 + ty + i * 8) * C + c0 + tx];
    __syncthreads();
#pragma unroll
    for (int i = 0; i < 4; ++i)
        out[(size_t)(c0 + ty + i * 8) * R + r0 + tx] = f2bf(t[tx][ty + i * 8]);
}

// ---------------- V transpose: qkvb V-part -> vtg[bh][64][2048] bf16 ----------------
__global__ __launch_bounds__(256) void vtrans_kernel(const unsigned short* __restrict__ qkvb,
                                                     unsigned short* __restrict__ vtg) {
    __shared__ unsigned short t[64 * 66];
    const int tid = threadIdx.x;
    const int t0 = blockIdx.x * 64;
    const int bh = blockIdx.y;
    const int b = bh >> 4, h = bh & 15;
    const unsigned short* src = qkvb + (size_t)(b * 2048 + t0) * 3072 + 2048 + h * 64;
#pragma unroll
    for (int c = 0; c < 2; ++c) {
        int cid = c * 256 + tid;
        int row = cid >> 3, cc = cid & 7;
        *(int4*)&t[row * 66 + cc * 8] = *(const int4*)&src[(size_t)row * 3072 + cc * 8];
    }
    __syncthreads();
    unsigned short* dst = vtg + (size_t)bh * 64 * 2048 + t0;
#pragma unroll
    for (int c = 0; c < 2; ++c) {
        int cid = c * 256 + tid;
        int d = cid >> 3, cc2 = cid & 7;
        bf16x8 v;
#pragma unroll
        for (int j = 0; j < 8; ++j) v[j] = (short)t[(cc2 * 8 + j) * 66 + d];
        *(bf16x8*)&dst[(size_t)d * 2048 + cc2 * 8] = v;
    }
}

// ---------------- GEMM 256x256, BK=64, 8 waves (2Mx4N), 4-phase counted-vmcnt -------
// Grouped work-id: per-XCD chunk covers GM A-panels x full nt sweep -> A resident in
// XCD L2, B streamed once (fixes 5.8x B-panel thrash seen at mt-outer mapping).
template <int ACT, int OBF>
__global__ __launch_bounds__(512, 2) void gemm256_kernel(
    const unsigned short* __restrict__ A, const unsigned short* __restrict__ Bt,
    const float* __restrict__ bias, void* __restrict__ out,
    int N, int K, int gridNt, int GM) {
    __shared__ __align__(16) unsigned short lA[2][256 * 64];
    __shared__ __align__(16) unsigned short lB[2][256 * 64];
    const int tid = threadIdx.x;
    const int lane = tid & 63, wid = tid >> 6;
    const int g = lane >> 4, lr = lane & 15;
    const int wm = wid >> 2, wn = wid & 3;

    const int nwg = gridDim.x, cpx = nwg >> 3, bid = blockIdx.x;
    const int wkid = (bid & 7) * cpx + (bid >> 3);
    const int mt = (wkid / (GM * gridNt)) * GM + (wkid % GM);
    const int nt = (wkid / GM) % gridNt;
    const int m0 = mt * 256, n0 = nt * 256;

    auto stageA = [&](int s, int kt, int bb) {  // s in [0,4): covers kb 2s..2s+1
        int c = s * 512 + tid;
        int row = c & 255, kb = c >> 8;
        gload16(&A[(size_t)(m0 + row) * K + kt * 64 + kb * 8],
                &lA[bb][(size_t)(s * 512 + (tid & ~63)) * 8]);
    };
    auto stageB = [&](int s, int kt, int bb) {
        int c = s * 512 + tid;
        int row = c & 255, kb = c >> 8;
        gload16(&Bt[(size_t)(n0 + row) * K + kt * 64 + kb * 8],
                &lB[bb][(size_t)(s * 512 + (tid & ~63)) * 8]);
    };

    f32x4 acc[8][4] = {};
    bf16x8 bfr[4];
    const int nkt = K >> 6;

    // prologue: tile 0 in group order {A01}{B01}{A23}{B23}
    stageA(0, 0, 0); stageA(1, 0, 0); stageB(0, 0, 0); stageB(1, 0, 0);
    stageA(2, 0, 0); stageA(3, 0, 0); stageB(2, 0, 0); stageB(3, 0, 0);
    asm volatile("s_waitcnt vmcnt(4)" ::: "memory");
    __builtin_amdgcn_s_barrier();
    asm volatile("" ::: "memory");

    for (int kt = 0; kt < nkt; ++kt) {
        const int buf = kt & 1;
        const bool more = (kt + 1 < nkt);
#pragma unroll
        for (int p = 0; p < 4; ++p) {
            const int ks = p >> 1, mh = p & 1;
            bf16x8 af[4];
#pragma unroll
            for (int mf2 = 0; mf2 < 4; ++mf2) {
                int c = (ks * 4 + g) * 256 + wm * 128 + (mh * 4 + mf2) * 16 + lr;
                af[mf2] = *(const bf16x8*)&lA[buf][(size_t)c * 8];
            }
            if (mh == 0) {
#pragma unroll
                for (int nf = 0; nf < 4; ++nf) {
                    int c = (ks * 4 + g) * 256 + wn * 64 + nf * 16 + lr;
                    bfr[nf] = *(const bf16x8*)&lB[buf][(size_t)c * 8];
                }
            }
            if (more) {
                if (p == 0)      { stageA(0, kt + 1, buf ^ 1); stageA(1, kt + 1, buf ^ 1); }
                else if (p == 1) { stageB(0, kt + 1, buf ^ 1); stageB(1, kt + 1, buf ^ 1); }
                else if (p == 2) { stageA(2, kt + 1, buf ^ 1); stageA(3, kt + 1, buf ^ 1); }
                else             { stageB(2, kt + 1, buf ^ 1); stageB(3, kt + 1, buf ^ 1); }
            }
            __builtin_amdgcn_s_barrier();
            asm volatile("s_waitcnt lgkmcnt(0)" ::: "memory");
            __builtin_amdgcn_sched_barrier(0);
            __builtin_amdgcn_s_setprio(1);
#pragma unroll
            for (int mf2 = 0; mf2 < 4; ++mf2)
#pragma unroll
                for (int nf = 0; nf < 4; ++nf)
                    acc[mh * 4 + mf2][nf] = __builtin_amdgcn_mfma_f32_16x16x32_bf16(
                        af[mf2], bfr[nf], acc[mh * 4 + mf2][nf], 0, 0, 0);
            __builtin_amdgcn_s_setprio(0);
            __builtin_amdgcn_sched_barrier(0);
            if (p == 1) {
                if (more) asm volatile("s_waitcnt vmcnt(4)" ::: "memory");
                else      asm volatile("s_waitcnt vmcnt(0)" ::: "memory");
            } else if (p == 3) {
                if (more) asm volatile("s_waitcnt vmcnt(4)" ::: "memory");
            }
            __builtin_amdgcn_s_barrier();
            asm volatile("" ::: "memory");
        }
    }

    // epilogue: bias (+GELU) and store
#pragma unroll
    for (int mf = 0; mf < 8; ++mf) {
#pragma unroll
        for (int nf = 0; nf < 4; ++nf) {
            int col = n0 + wn * 64 + nf * 16 + lr;
            float bv = bias[col];
#pragma unroll
            for (int r = 0; r < 4; ++r) {
                int row = m0 + wm * 128 + mf * 16 + g * 4 + r;
                float v = acc[mf][nf][r] + bv;
                if (ACT == 1) v = gelu_f(v);
                if (OBF)
                    ((unsigned short*)out)[(size_t)row * N + col] = f2bf(v);
                else
                    ((float*)out)[(size_t)row * N + col] = v;
            }
        }
    }
}

// ---------------- GEMM 128x256, BK=64, 8 waves (2Mx4N), 2-phase counted-vmcnt ------
template <int ACT, int OBF>
__global__ __launch_bounds__(512, 2) void gemm128_kernel(
    const unsigned short* __restrict__ A, const unsigned short* __restrict__ Bt,
    const float* __restrict__ bias, void* __restrict__ out,
    int N, int K, int gridNt, int GM) {
    __shared__ __align__(16) unsigned short lA[2][128 * 64];
    __shared__ __align__(16) unsigned short lB[2][256 * 64];
    const int tid = threadIdx.x;
    const int lane = tid & 63, wid = tid >> 6;
    const int g = lane >> 4, lr = lane & 15;
    const int wm = wid >> 2, wn = wid & 3;

    const int nwg = gridDim.x, cpx = nwg >> 3, bid = blockIdx.x;
    const int wkid = (bid & 7) * cpx + (bid >> 3);
    const int mt = (wkid / (GM * gridNt)) * GM + (wkid % GM);
    const int nt = (wkid / GM) % gridNt;
    const int m0 = mt * 128, n0 = nt * 256;

    auto stageA = [&](int s, int kt, int bb) {  // s in [0,2): covers kb 4s..4s+3
        int c = s * 512 + tid;
        int row = c & 127, kb = c >> 7;
        gload16(&A[(size_t)(m0 + row) * K + kt * 64 + kb * 8],
                &lA[bb][(size_t)(s * 512 + (tid & ~63)) * 8]);
    };
    auto stageB = [&](int s, int kt, int bb) {
        int c = s * 512 + tid;
        int row = c & 255, kb = c >> 8;
        gload16(&Bt[(size_t)(n0 + row) * K + kt * 64 + kb * 8],
                &lB[bb][(size_t)(s * 512 + (tid & ~63)) * 8]);
    };

    f32x4 acc[4][4] = {};
    const int nkt = K >> 6;

    // prologue: tile 0 in group order {A0,B0,B1}{A1,B2,B3}
    stageA(0, 0, 0); stageB(0, 0, 0); stageB(1, 0, 0);
    stageA(1, 0, 0); stageB(2, 0, 0); stageB(3, 0, 0);
    asm volatile("s_waitcnt vmcnt(3)" ::: "memory");
    __builtin_amdgcn_s_barrier();
    asm volatile("" ::: "memory");

    for (int kt = 0; kt < nkt; ++kt) {
        const int buf = kt & 1;
        const bool more = (kt + 1 < nkt);
#pragma unroll
        for (int ks = 0; ks < 2; ++ks) {
            bf16x8 af[4], bfr[4];
#pragma unroll
            for (int mf = 0; mf < 4; ++mf) {
                int c = (ks * 4 + g) * 128 + wm * 64 + mf * 16 + lr;
                af[mf] = *(const bf16x8*)&lA[buf][(size_t)c * 8];
            }
#pragma unroll
            for (int nf = 0; nf < 4; ++nf) {
                int c = (ks * 4 + g) * 256 + wn * 64 + nf * 16 + lr;
                bfr[nf] = *(const bf16x8*)&lB[buf][(size_t)c * 8];
            }
            if (more) {
                if (ks == 0) { stageA(0, kt + 1, buf ^ 1); stageB(0, kt + 1, buf ^ 1); stageB(1, kt + 1, buf ^ 1); }
                else         { stageA(1, kt + 1, buf ^ 1); stageB(2, kt + 1, buf ^ 1); stageB(3, kt + 1, buf ^ 1); }
            }
            __builtin_amdgcn_s_barrier();
            asm volatile("s_waitcnt lgkmcnt(0)" ::: "memory");
            __builtin_amdgcn_sched_barrier(0);
            __builtin_amdgcn_s_setprio(1);
#pragma unroll
            for (int mf = 0; mf < 4; ++mf)
#pragma unroll
                for (int nf = 0; nf < 4; ++nf)
                    acc[mf][nf] = __builtin_amdgcn_mfma_f32_16x16x32_bf16(
                        af[mf], bfr[nf], acc[mf][nf], 0, 0, 0);
            __builtin_amdgcn_s_setprio(0);
            __builtin_amdgcn_sched_barrier(0);
            if (ks == 0) {
                if (more) asm volatile("s_waitcnt vmcnt(3)" ::: "memory");
                else      asm volatile("s_waitcnt vmcnt(0)" ::: "memory");
            } else {
                if (more) asm volatile("s_waitcnt vmcnt(3)" ::: "memory");
            }
            __builtin_amdgcn_s_barrier();
            asm volatile("" ::: "memory");
        }
    }

#pragma unroll
    for (int mf = 0; mf < 4; ++mf) {
#pragma unroll
        for (int nf = 0; nf < 4; ++nf) {
            int col = n0 + wn * 64 + nf * 16 + lr;
            float bv = bias[col];
#pragma unroll
            for (int r = 0; r < 4; ++r) {
                int row = m0 + wm * 64 + mf * 16 + g * 4 + r;
                float v = acc[mf][nf][r] + bv;
                if (ACT == 1) v = gelu_f(v);
                if (OBF)
                    ((unsigned short*)out)[(size_t)row * N + col] = f2bf(v);
                else
                    ((float*)out)[(size_t)row * N + col] = v;
            }
        }
    }
}

// ---------------- flash attention v4: KVBLK=128, defer-max, bh->XCD affinity --------
__global__ __launch_bounds__(256, 2) void attn_kernel(const unsigned short* __restrict__ qkv,
                                                      const unsigned short* __restrict__ vtg,
                                                      unsigned short* __restrict__ y) {
    __shared__ unsigned short Kl[2][128 * 64];
    __shared__ unsigned short Vl[2][64 * 128];
    const int tid = threadIdx.x, lane = tid & 63, w = tid >> 6;
    const int g = lane >> 4, lr = lane & 15;
    const int id = blockIdx.x + 8 * (blockIdx.y + 16 * blockIdx.z);
    const int xcd = id & 7, wrk = id >> 3;
    const int bh = xcd * 8 + (wrk & 7);
    const int p = wrk >> 3;
    const int b = bh >> 4, h = bh & 15;
    const size_t rs3 = 3072;
    const unsigned short* qbase = qkv + (size_t)b * 2048 * rs3 + h * 64;
    const unsigned short* kbase = qbase + 1024;
    const unsigned short* vbase = vtg + (size_t)bh * 64 * 2048;

    int ksoff[4], vsoff[4], ldoff[4];
#pragma unroll
    for (int c = 0; c < 4; ++c) {
        int cid = c * 256 + tid;
        int krow = cid >> 3, kcc = cid & 7;
        ksoff[c] = krow * 3072 + (kcc ^ (krow & 7) ^ ((krow >> 3) & 7)) * 8;
        int d = cid >> 4, tcs = cid & 15;
        vsoff[c] = d * 2048 + (tcs ^ ((d & 7) ^ ((d >> 3) & 7))) * 8;
        ldoff[c] = (c * 256 + (tid & ~63)) * 8;
    }

    const int idxP0 = 4 * (32 * (g & 1) + lr);
    const int idxP1 = idxP0 + 64;
    int idxA[4];
#pragma unroll
    for (int r = 0; r < 4; ++r) idxA[r] = 4 * (g * 20 + r);
    const bool ghigh = (g >> 1) != 0;
    const float qscale = 0.125f * 1.44269504089f;

    auto process = [&](int J) {
        const int q0w = J * 128 + w * 32;
        const int ktend = J + 1;
#pragma unroll
        for (int c = 0; c < 4; ++c) {
            gload16(&kbase[ksoff[c]], &Kl[0][ldoff[c]]);
            gload16(&vbase[vsoff[c]], &Vl[0][ldoff[c]]);
        }
        int qf[2][2][4];
#pragma unroll
        for (int sub = 0; sub < 2; ++sub)
#pragma unroll
            for (int f = 0; f < 2; ++f) {
                int4 v = *(const int4*)&qbase[(size_t)(q0w + sub * 16 + lr) * rs3 + f * 32 + g * 8];
                int vv[4] = {v.x, v.y, v.z, v.w};
#pragma unroll
                for (int i = 0; i < 4; ++i) {
                    unsigned int u = (unsigned int)vv[i];
                    float lo = __builtin_bit_cast(float, u << 16) * qscale;
                    float hi = __builtin_bit_cast(float, u & 0xffff0000u) * qscale;
                    qf[sub][f][i] = cvtpk_bf16(lo, hi);
                }
            }

        f32x4 O[2][4] = {};
        float m_[2] = {-3.0e38f, -3.0e38f}, l_[2] = {0.f, 0.f};

        int buf = 0;
        for (int kt = 0; kt < ktend; ++kt) {
            asm volatile("s_waitcnt vmcnt(0)" ::: "memory");
            __builtin_amdgcn_s_barrier();
            asm volatile("" ::: "memory");
            if (kt + 1 < ktend) {
#pragma unroll
                for (int c = 0; c < 4; ++c) {
                    gload16(&kbase[(size_t)(kt + 1) * 128 * 3072 + ksoff[c]], &Kl[buf ^ 1][ldoff[c]]);
                    gload16(&vbase[vsoff[c] + (kt + 1) * 128], &Vl[buf ^ 1][ldoff[c]]);
                }
            }
            const unsigned short* Kc = Kl[buf];
            const unsigned short* Vc = Vl[buf];

            f32x4 s0[8], s1[8];
#pragma unroll
            for (int st = 0; st < 8; ++st) {
                int rbase = (st * 16 + lr) * 64;
                int sw = (lr & 7) ^ ((st * 2 + (lr >> 3)) & 7);
                bf16x8 kf0 = *(const bf16x8*)&Kc[rbase + ((g ^ sw) * 8)];
                bf16x8 kf1 = *(const bf16x8*)&Kc[rbase + (((4 + g) ^ sw) * 8)];
                f32x4 a = {};
                a = __builtin_amdgcn_mfma_f32_16x16x32_bf16(kf0, *(const bf16x8*)&qf[0][0], a, 0, 0, 0);
                a = __builtin_amdgcn_mfma_f32_16x16x32_bf16(kf1, *(const bf16x8*)&qf[0][1], a, 0, 0, 0);
                s0[st] = a;
                f32x4 c = {};
                c = __builtin_amdgcn_mfma_f32_16x16x32_bf16(kf0, *(const bf16x8*)&qf[1][0], c, 0, 0, 0);
                c = __builtin_amdgcn_mfma_f32_16x16x32_bf16(kf1, *(const bf16x8*)&qf[1][1], c, 0, 0, 0);
                s1[st] = c;
            }

            int wt0[4][4], wt1[4][4];
#pragma unroll
            for (int sub = 0; sub < 2; ++sub) {
                f32x4* s = (sub == 0) ? s0 : s1;
                const int qmin = q0w + sub * 16;
                if (kt == J) {
                    int qv = qmin + lr;
#pragma unroll
                    for (int st = 0; st < 8; ++st) {
                        int keyb = kt * 128 + st * 16 + g * 4;
#pragma unroll
                        for (int r = 0; r < 4; ++r)
                            if (keyb + r > qv) s[st][r] = -3.0e38f;
                    }
                }
                float mx = fmaxf(fmaxf(s[0][0], s[0][1]), fmaxf(s[0][2], s[0][3]));
#pragma unroll
                for (int st = 1; st < 8; ++st)
                    mx = fmaxf(mx, fmaxf(fmaxf(s[st][0], s[st][1]), fmaxf(s[st][2], s[st][3])));
                mx = fmaxf(mx, __shfl_xor(mx, 16));
                mx = fmaxf(mx, __shfl_xor(mx, 32));
                if (__any(mx - m_[sub] > 11.5f)) {
                    float mnew = fmaxf(m_[sub], mx);
                    float alpha = __builtin_amdgcn_exp2f(m_[sub] - mnew);
                    m_[sub] = mnew;
                    l_[sub] *= alpha;
                    int av = __builtin_bit_cast(int, alpha);
                    f32x4* Os = O[sub];
#pragma unroll
                    for (int r = 0; r < 4; ++r) {
                        float ar = __builtin_bit_cast(float, __builtin_amdgcn_ds_bpermute(idxA[r], av));
#pragma unroll
                        for (int dt = 0; dt < 4; ++dt) Os[dt][r] *= ar;
                    }
                }
                float rs = 0.f;
#pragma unroll
                for (int st = 0; st < 8; ++st)
#pragma unroll
                    for (int r = 0; r < 4; ++r) {
                        float pp = __builtin_amdgcn_exp2f(s[st][r] - m_[sub]);
                        s[st][r] = pp;
                        rs += pp;
                    }
                rs += __shfl_xor(rs, 16);
                rs += __shfl_xor(rs, 32);
                l_[sub] += rs;
                int ws_[8][2];
#pragma unroll
                for (int st = 0; st < 8; ++st) {
                    ws_[st][0] = cvtpk_bf16(s[st][0], s[st][1]);
                    ws_[st][1] = cvtpk_bf16(s[st][2], s[st][3]);
                }
                int(*wt)[4] = (sub == 0) ? wt0 : wt1;
#pragma unroll
                for (int ks = 0; ks < 4; ++ks)
#pragma unroll
                    for (int hp = 0; hp < 4; ++hp) {
                        int idx = (hp < 2) ? idxP0 : idxP1;
                        int v0 = __builtin_amdgcn_ds_bpermute(idx, ws_[2 * ks][hp & 1]);
                        int v1 = __builtin_amdgcn_ds_bpermute(idx, ws_[2 * ks + 1][hp & 1]);
                        wt[ks][hp] = ghigh ? v1 : v0;
                    }
            }

#pragma unroll
            for (int ks = 0; ks < 4; ++ks) {
                bf16x8 pa0 = *(const bf16x8*)&wt0[ks][0];
                bf16x8 pa1 = *(const bf16x8*)&wt1[ks][0];
#pragma unroll
                for (int dt = 0; dt < 4; ++dt) {
                    int d = dt * 16 + lr;
                    int tc = (ks * 4 + g) ^ ((lr & 7) ^ ((dt * 2 + (lr >> 3)) & 7));
                    bf16x8 vf = *(const bf16x8*)&Vc[d * 128 + tc * 8];
                    O[0][dt] = __builtin_amdgcn_mfma_f32_16x16x32_bf16(pa0, vf, O[0][dt], 0, 0, 0);
                    O[1][dt] = __builtin_amdgcn_mfma_f32_16x16x32_bf16(pa1, vf, O[1][dt], 0, 0, 0);
                }
            }
            buf ^= 1;
        }

#pragma unroll
        for (int sub = 0; sub < 2; ++sub) {
            int lv = __builtin_bit_cast(int, l_[sub]);
#pragma unroll
            for (int r = 0; r < 4; ++r) {
                float lval = __builtin_bit_cast(float, __builtin_amdgcn_ds_bpermute(idxA[r], lv));
                float inv = __builtin_amdgcn_rcpf(lval);
                int q = q0w + sub * 16 + g * 4 + r;
#pragma unroll
                for (int dt = 0; dt < 4; ++dt)
                    y[(size_t)(b * 2048 + q) * 1024 + h * 64 + dt * 16 + lr] =
                        f2bf(O[sub][dt][r] * inv);
            }
        }
    };

    process(15 - p);
    __syncthreads();
    process(p);
}

// ---------------- residual + layernorm: out = base + LN(delta)*g+b ----------------
template <int WRITE_BF>
__global__ __launch_bounds__(256) void ln_kernel(const float* __restrict__ base,
                                                 const float* __restrict__ delta,
                                                 const float* __restrict__ gw,
                                                 const float* __restrict__ bw,
                                                 float* __restrict__ outf,
                                                 unsigned short* __restrict__ outb) {
    const int row = blockIdx.x;
    const int tid = threadIdx.x;
    const float* d = delta + (size_t)row * 1024;
    const float* bs = base + (size_t)row * 1024;
    float4 x = *(const float4*)&d[tid * 4];
    float s = x.x + x.y + x.z + x.w;
    float s2 = x.x * x.x + x.y * x.y + x.z * x.z + x.w * x.w;
#pragma unroll
    for (int off = 1; off < 64; off <<= 1) {
        s += __shfl_xor(s, off);
        s2 += __shfl_xor(s2, off);
    }
    __shared__ float red[8];
    if ((tid & 63) == 0) {
        red[tid >> 6] = s;
        red[4 + (tid >> 6)] = s2;
    }
    __syncthreads();
    s = red[0] + red[1] + red[2] + red[3];
    s2 = red[4] + red[5] + red[6] + red[7];
    float mu = s * (1.f / 1024.f);
    float var = s2 * (1.f / 1024.f) - mu * mu;
    float rsig = rsqrtf(var + 1e-5f);
    float4 bb = *(const float4*)&bs[tid * 4];
    float4 gv = *(const float4*)&gw[tid * 4];
    float4 bv = *(const float4*)&bw[tid * 4];
    float4 o;
    o.x = bb.x + (x.x - mu) * rsig * gv.x + bv.x;
    o.y = bb.y + (x.y - mu) * rsig * gv.y + bv.y;
    o.z = bb.z + (x.z - mu) * rsig * gv.z + bv.z;
    o.w = bb.w + (x.w - mu) * rsig * gv.w + bv.w;
    *(float4*)&outf[(size_t)row * 1024 + tid * 4] = o;
    if (WRITE_BF) {
        unsigned short* ob = outb + (size_t)row * 1024 + tid * 4;
        ob[0] = f2bf(o.x);
        ob[1] = f2bf(o.y);
        ob[2] = f2bf(o.z);
        ob[3] = f2bf(o.w);
    }
}

extern "C" void kernel_launch(void* const* d_in, const int* in_sizes, int n_in,
                              void* d_out, int out_size, void* d_ws, size_t ws_size,
                              hipStream_t stream) {
    const float* x = (const float*)d_in[0];
    const float* w_qkv = (const float*)d_in[1];
    const float* b_qkv = (const float*)d_in[2];
    const float* w_out = (const float*)d_in[3];
    const float* b_out = (const float*)d_in[4];
    const float* w1 = (const float*)d_in[5];
    const float* b1 = (const float*)d_in[6];
    const float* w2 = (const float*)d_in[7];
    const float* b2 = (const float*)d_in[8];
    const float* g1 = (const float*)d_in[9];
    const float* be1 = (const float*)d_in[10];
    const float* g2 = (const float*)d_in[11];
    const float* be2 = (const float*)d_in[12];

    const size_t MB = 1ull << 20;
    if (ws_size < 184 * MB) return;
    char* ws = (char*)d_ws;
    unsigned short* xb    = (unsigned short*)(ws + 0);         // 16MB (dead after qkv gemm)
    unsigned short* vtg   = (unsigned short*)(ws + 0);         // 16MB (V^T, lives during attn)
    unsigned short* wqkvt = (unsigned short*)(ws + 16 * MB);   // 6MB
    unsigned short* qkvb  = (unsigned short*)(ws + 22 * MB);   // 48MB
    unsigned short* hb    = (unsigned short*)(ws + 0);         // 64MB (reuse, MLP phase)
    unsigned short* woutt = (unsigned short*)(ws + 70 * MB);   // 2MB
    unsigned short* yb    = (unsigned short*)(ws + 72 * MB);   // 16MB
    float*          attnp = (float*)(ws + 88 * MB);            // 32MB
    float*          ff    = (float*)(ws + 88 * MB);            // 32MB (reuse)
    float*          x2f   = (float*)(ws + 120 * MB);           // 32MB
    unsigned short* x2b   = (unsigned short*)(ws + 152 * MB);  // 16MB
    unsigned short* w1t   = (unsigned short*)(ws + 168 * MB);  // 8MB
    unsigned short* w2t   = (unsigned short*)(ws + 176 * MB);  // 8MB

    // prep
    cvtbf_kernel<<<8192, 256, 0, stream>>>(x, xb);
    transpose_cvt_kernel<<<dim3(96, 32), dim3(32, 8), 0, stream>>>(w_qkv, wqkvt, 1024, 3072);
    transpose_cvt_kernel<<<dim3(32, 32), dim3(32, 8), 0, stream>>>(w_out, woutt, 1024, 1024);
    transpose_cvt_kernel<<<dim3(128, 32), dim3(32, 8), 0, stream>>>(w1, w1t, 1024, 4096);
    transpose_cvt_kernel<<<dim3(32, 128), dim3(32, 8), 0, stream>>>(w2, w2t, 4096, 1024);
    // qkv = x @ w_qkv + b_qkv (bf16 out) [M=8192 N=3072 K=1024]: 32mt x 12nt, GM=4
    gemm256_kernel<0, 1><<<384, 512, 0, stream>>>(xb, wqkvt, b_qkv, qkvb, 3072, 1024, 12, 4);
    // V^T pre-transpose
    vtrans_kernel<<<dim3(32, 64), 256, 0, stream>>>(qkvb, vtg);
    // attention
    attn_kernel<<<dim3(8, 16, 4), 256, 0, stream>>>(qkvb, vtg, yb);
    // out proj (f32 out) [N=1024 K=1024]: 64mt x 4nt, GM=8
    gemm128_kernel<0, 0><<<256, 512, 0, stream>>>(yb, woutt, b_out, attnp, 1024, 1024, 4, 8);
    // x2 = x + LN(attnp)
    ln_kernel<1><<<8192, 256, 0, stream>>>(x, attnp, g1, be1, x2f, x2b);
    // h = gelu(x2 @ w1 + b1) (bf16 out) [N=4096 K=1024]: 32mt x 16nt, GM=4
    gemm256_kernel<1, 1><<<512, 512, 0, stream>>>(x2b, w1t, b1, hb, 4096, 1024, 16, 4);
    // f = h @ w2 + b2 (f32 out) [N=1024 K=4096]: 64mt x 4nt, GM=8
    gemm128_kernel<0, 0><<<256, 512, 0, stream>>>(hb, w2t, b2, ff, 1024, 4096, 4, 8);
    // out = x2 + LN(f)
    ln_kernel<0><<<8192, 256, 0, stream>>>(x2f, ff, g2, be2, (float*)d_out, nullptr);
}